// Round 7
// baseline (128.110 us; speedup 1.0000x reference)
//
#include <hip/hip_runtime.h>
#include <stdint.h>

// Problem constants
#define B_   2
#define S_   2048
#define HID  1024
#define NH   16
#define CH   64
#define MTOT (B_ * S_)          // 4096 rows
#define NELEM ((size_t)MTOT * HID)   // 4,194,304 per matrix
#define WELEM ((size_t)HID * HID)    // 1,048,576 per weight

typedef unsigned short u16;
typedef __attribute__((ext_vector_type(4))) float f32x4;
typedef __attribute__((ext_vector_type(8))) short s16x8;

// ---------- helpers ----------
__device__ __forceinline__ u16 f2bf(float f) {
  union { float f; unsigned u; } v; v.f = f;
  unsigned u = v.u;
  return (u16)((u + 0x7FFFu + ((u >> 16) & 1u)) >> 16);  // RNE (R3/R4-verified)
}

__device__ __forceinline__ f32x4 mfma16(s16x8 a, s16x8 b, f32x4 c) {
  // v_mfma_f32_16x16x32_bf16: A row = lane&15, k = (lane>>4)*8+j (contig 16B);
  // B col = lane&15, same k; D col = lane&15, row = (lane>>4)*4+reg (m89-verified).
  asm("v_mfma_f32_16x16x32_bf16 %0, %1, %2, %0" : "+v"(c) : "v"(a), "v"(b));
  return c;
}

// Hazard-hardened variant for k_attn (R5/R6 failure theory):
//  - s_nop 1 (2 cyc) guards the CDNA "VALU write -> MFMA read SrcA/B/C"
//    2-cycle rule — the per-step acc={0} v_movs can be scheduled adjacent
//    to the MFMA in the lean 16-row-wave body.
//  - "+&v" early-clobber forbids the allocator from aliasing A/B input
//    registers with the D output (arch-unsafe for MFMA).
__device__ __forceinline__ f32x4 mfma16h(s16x8 a, s16x8 b, f32x4 c) {
  asm("s_nop 1\n\tv_mfma_f32_16x16x32_bf16 %0, %1, %2, %0"
      : "+&v"(c) : "v"(a), "v"(b));
  return c;
}

__device__ __forceinline__ void mfma_fence() {
  asm volatile("s_nop 7\n\ts_nop 7" ::: );
}

__device__ __forceinline__ void gload_lds16(const u16* g, u16* l) {
  __builtin_amdgcn_global_load_lds((const __attribute__((address_space(1))) void*)g,
                                   (__attribute__((address_space(3))) void*)l,
                                   16, 0, 0);
}

// ---------- kernel 1: fp32 -> bf16 convert of q,k,v ----------
__global__ __launch_bounds__(256) void k_convert(const float* __restrict__ a,
                                                 const float* __restrict__ b,
                                                 const float* __restrict__ c,
                                                 u16* __restrict__ out) {
  const float* src = (blockIdx.y == 0) ? a : (blockIdx.y == 1) ? b : c;
  u16* dst = out + (size_t)blockIdx.y * NELEM;
  size_t i = ((size_t)blockIdx.x * 256 + threadIdx.x) * 8;
  f32x4 v0 = *(const f32x4*)(src + i);
  f32x4 v1 = *(const f32x4*)(src + i + 4);
  s16x8 r;
#pragma unroll
  for (int k = 0; k < 4; ++k) { r[k] = (short)f2bf(v0[k]); r[4 + k] = (short)f2bf(v1[k]); }
  *(s16x8*)(dst + i) = r;
}

// ---------- kernel 2: W (fp32 [K][N]) -> W^T (bf16 [N][K]) ----------
__global__ __launch_bounds__(256) void k_transposeW(const float* __restrict__ w0,
                                                    const float* __restrict__ w1,
                                                    const float* __restrict__ w2,
                                                    u16* __restrict__ wT) {
  const float* w = (blockIdx.z == 0) ? w0 : (blockIdx.z == 1) ? w1 : w2;
  u16* o = wT + (size_t)blockIdx.z * WELEM;
  __shared__ u16 tile[64][65];
  int x = threadIdx.x & 63, y = threadIdx.x >> 6;
  int r0 = blockIdx.x * 64, c0 = blockIdx.y * 64;
#pragma unroll
  for (int i = 0; i < 16; ++i) {
    int r = i * 4 + y;
    tile[r][x] = f2bf(w[(size_t)(r0 + r) * HID + c0 + x]);
  }
  __syncthreads();
#pragma unroll
  for (int i = 0; i < 16; ++i) {
    int cc = i * 4 + y;
    o[(size_t)(c0 + cc) * HID + r0 + x] = tile[x][cc];
  }
}

// ---------- kernel 3: bf16 GEMM  C[M,N] = A[M,K] @ (BT[N,K])^T ----------
// m97 structure: 128x128 tile, BK=32, 4 waves in 2x2, global_load_lds width 16.
// z==0 (emb_q) is scaled by 1/sqrt(CH) so attention needs no per-score scale.
__global__ __launch_bounds__(256) void k_gemm(const u16* __restrict__ Aall,
                                              const u16* __restrict__ BTall,
                                              u16* __restrict__ Call) {
  const u16* A  = Aall  + (size_t)blockIdx.z * NELEM;
  const u16* BT = BTall + (size_t)blockIdx.z * WELEM;
  u16*       C  = Call  + (size_t)blockIdx.z * NELEM;
  int row0 = blockIdx.y * 128, col0 = blockIdx.x * 128;

  __shared__ __align__(16) u16 sA[128 * 32];
  __shared__ __align__(16) u16 sB[128 * 32];

  int t = threadIdx.x;
  int wave = t >> 6, lane = t & 63;
  int lrow = lane & 15, lhi = lane >> 4;
  int wr = wave >> 1, wc = wave & 1;

  f32x4 acc[4][4] = {};

  for (int kt = 0; kt < HID; kt += 32) {
#pragma unroll
    for (int r = 0; r < 2; ++r) {
      int idx = r * 256 + t;
      int srow = idx >> 2, scol = (idx & 3) << 3;
      int ldsoff = (r * 256 + wave * 64) * 8;   // wave-uniform LDS base
      gload_lds16(A  + (size_t)(row0 + srow) * HID + kt + scol, sA + ldsoff);
      gload_lds16(BT + (size_t)(col0 + srow) * HID + kt + scol, sB + ldsoff);
    }
    __syncthreads();
    s16x8 af[4], bfr[4];
#pragma unroll
    for (int m = 0; m < 4; ++m)
      af[m] = *(const s16x8*)&sA[(wr * 64 + m * 16 + lrow) * 32 + lhi * 8];
#pragma unroll
    for (int n = 0; n < 4; ++n)
      bfr[n] = *(const s16x8*)&sB[(wc * 64 + n * 16 + lrow) * 32 + lhi * 8];
#pragma unroll
    for (int m = 0; m < 4; ++m)
#pragma unroll
      for (int n = 0; n < 4; ++n)
        acc[m][n] = mfma16(af[m], bfr[n], acc[m][n]);
    __syncthreads();
  }
  mfma_fence();
  float scl = (blockIdx.z == 0) ? 0.125f : 1.0f;   // fold 1/sqrt(64) into emb_q
#pragma unroll
  for (int m = 0; m < 4; ++m)
#pragma unroll
    for (int n = 0; n < 4; ++n)
#pragma unroll
      for (int j = 0; j < 4; ++j) {
        int rr = row0 + wr * 64 + m * 16 + lhi * 4 + j;
        int cc = col0 + wc * 64 + n * 16 + lrow;
        C[(size_t)rr * HID + cc] = f2bf(acc[m][n][j] * scl);
      }
}

// ---------- kernel 4: emb_v [B*S, HID] -> V^T [B,H,CH,S] ----------
__global__ __launch_bounds__(256) void k_transposeV(const u16* __restrict__ ev,
                                                    u16* __restrict__ vt) {
  int x = threadIdx.x & 63, y = threadIdx.x >> 6;
  int s0 = blockIdx.x * 64;
  int h = blockIdx.y, b = blockIdx.z;
  __shared__ u16 tile[64][65];
#pragma unroll
  for (int i = 0; i < 16; ++i) {
    int r = i * 4 + y;
    tile[r][x] = ev[(size_t)(b * S_ + s0 + r) * HID + h * CH + x];
  }
  __syncthreads();
#pragma unroll
  for (int i = 0; i < 16; ++i) {
    int cc = i * 4 + y;
    vt[((size_t)(b * NH + h) * CH + cc) * S_ + s0 + x] = tile[x][cc];
  }
}

// ---------- kernel 5: causal flash attention ----------
// Structure identical to R6 (QTILE=64, 4 waves x 16 q-rows, KVBLK=64, K/V in
// LDS double-buffered via global_load_lds with XOR swizzle, fixed-max softmax,
// deferred row-sum). ONLY change vs R6: all MFMAs use the hazard-hardened
// mfma16h (s_nop SrcC guard + early-clobber D).
__global__ __launch_bounds__(256) void k_attn(const u16* __restrict__ eq,
                                              const u16* __restrict__ ek,
                                              const u16* __restrict__ vt,
                                              float* __restrict__ out) {
  int bh = blockIdx.y;                 // b*NH + h
  int b = bh >> 4, h = bh & 15;
  // causal load balance: pair q-tile k with 31-k across the two bh halves
  int qt = (blockIdx.y & 16) ? (int)blockIdx.x : (31 - (int)blockIdx.x);
  int q0b = qt * 64;
  int wave = threadIdx.x >> 6, lane = threadIdx.x & 63;
  int lrow = lane & 15, lhi = lane >> 4;
  int q0w = q0b + wave * 16;

  __shared__ __align__(16) u16 sK[2][64 * 64];
  __shared__ __align__(16) u16 sV[2][64 * 64];
  __shared__ __align__(16) u16 pbuf[4][16 * 72];   // P bounce, stride 72 (pad)
  u16* pb = pbuf[wave];

  const u16* gK = ek + (size_t)(b * S_) * HID + h * CH;
  const u16* gV = vt + (size_t)bh * CH * S_;

  // Q fragments held in registers (emb_q pre-scaled by 1/8 in GEMM)
  s16x8 qf[2];
  {
    size_t qbase = (size_t)(b * S_ + q0w + lrow) * HID + h * CH;
    qf[0] = *(const s16x8*)(eq + qbase + lhi * 8);
    qf[1] = *(const s16x8*)(eq + qbase + 32 + lhi * 8);
  }

  f32x4 o[4] = {};
  float lsum[4] = {0.f, 0.f, 0.f, 0.f};

  // staging lane mapping: 8 chunks/tile, chunk c covers rows c*8..c*8+7
  int lr8 = lane >> 3, slot = lane & 7;
  int co = ((slot ^ lr8) << 3);     // inverse-swizzled source column (elems)

  // prologue: stage tile 0 (wave stages chunks 2w, 2w+1 — R4-verified mapping)
#pragma unroll
  for (int i = 0; i < 2; ++i) {
    int c = wave * 2 + i;
    gload_lds16(gK + (size_t)(c * 8 + lr8) * HID + co, &sK[0][c * 512]);
    gload_lds16(gV + (size_t)(c * 8 + lr8) * S_  + co, &sV[0][c * 512]);
  }

  int nsteps = qt + 1;                     // tiles tb=0..q0b cover kv <= q0b+63
  for (int st = 0; st < nsteps; ++st) {
    int tb = st * 64;
    __syncthreads();                       // stage(st) complete in all waves
    if (st + 1 < nsteps) {                 // prefetch next tile into other buf
      int tb2 = tb + 64;
      int bufn = (st + 1) & 1;
#pragma unroll
      for (int i = 0; i < 2; ++i) {
        int c = wave * 2 + i;
        gload_lds16(gK + (size_t)(tb2 + c * 8 + lr8) * HID + co, &sK[bufn][c * 512]);
        // V^T: row = channel (stride S_), seq offset tb2 goes in the COLUMN
        gload_lds16(gV + (size_t)(c * 8 + lr8) * S_ + tb2 + co, &sV[bufn][c * 512]);
      }
    }
    if (tb > q0w + 15) continue;           // fully masked for this wave

    const u16* kb = sK[st & 1];
    const u16* vb = sV[st & 1];

    // ---- QK^T: 8 MFMA ----
    s16x8 kf[4][2];
#pragma unroll
    for (int kvf = 0; kvf < 4; ++kvf) {
      int row = kvf * 16 + lrow;
      int sw = row & 7;
#pragma unroll
      for (int ks = 0; ks < 2; ++ks)
        kf[kvf][ks] = *(const s16x8*)(kb + row * 64 + (((ks * 4 + lhi) ^ sw) << 3));
    }
    f32x4 sc[4];
#pragma unroll
    for (int kvf = 0; kvf < 4; ++kvf) {
      f32x4 acc = {0.f, 0.f, 0.f, 0.f};
      acc = mfma16h(qf[0], kf[kvf][0], acc);
      acc = mfma16h(qf[1], kf[kvf][1], acc);
      sc[kvf] = acc;
    }
    mfma_fence();

    // ---- softmax numerators (fixed max = 0), deferred denominator ----
    bool need_mask = (tb + 63 > q0w);
#pragma unroll
    for (int j = 0; j < 4; ++j) {
      float v0 = sc[0][j], v1 = sc[1][j], v2 = sc[2][j], v3 = sc[3][j];
      if (need_mask) {
        int qpos = q0w + lhi * 4 + j;
        if (tb + lrow > qpos)      v0 = -3.0e38f;
        if (tb + 16 + lrow > qpos) v1 = -3.0e38f;
        if (tb + 32 + lrow > qpos) v2 = -3.0e38f;
        if (tb + 48 + lrow > qpos) v3 = -3.0e38f;
      }
      float e0 = __expf(v0), e1 = __expf(v1);
      float e2 = __expf(v2), e3 = __expf(v3);
      lsum[j] += (e0 + e1) + (e2 + e3);
      int prow = (lhi * 4 + j) * 72;
      pb[prow + lrow]      = f2bf(e0);
      pb[prow + 16 + lrow] = f2bf(e1);
      pb[prow + 32 + lrow] = f2bf(e2);
      pb[prow + 48 + lrow] = f2bf(e3);
    }

    // ---- PV: 8 MFMA ----
#pragma unroll
    for (int kvs = 0; kvs < 2; ++kvs) {
      s16x8 pa = *(const s16x8*)&pb[lrow * 72 + kvs * 32 + lhi * 8];
#pragma unroll
      for (int ct = 0; ct < 4; ++ct) {
        int row = ct * 16 + lrow;
        s16x8 vf = *(const s16x8*)(vb + row * 64 + (((kvs * 4 + lhi) ^ (row & 7)) << 3));
        o[ct] = mfma16h(pa, vf, o[ct]);
      }
    }
  }
  mfma_fence();

  // deferred row-sum reduce (once, not per step)
#pragma unroll
  for (int j = 0; j < 4; ++j) {
    float rs = lsum[j];
    rs += __shfl_xor(rs, 1);
    rs += __shfl_xor(rs, 2);
    rs += __shfl_xor(rs, 4);
    rs += __shfl_xor(rs, 8);
    lsum[j] = rs;
  }

#pragma unroll
  for (int j = 0; j < 4; ++j) {
    float inv = 1.0f / lsum[j];
    int q = q0w + lhi * 4 + j;
    float* op = out + (size_t)(b * S_ + q) * HID + h * CH + lrow;
#pragma unroll
    for (int ct = 0; ct < 4; ++ct)
      op[ct * 16] = o[ct][j] * inv;
  }
}

// ---------- launch ----------
extern "C" void kernel_launch(void* const* d_in, const int* in_sizes, int n_in,
                              void* d_out, int out_size, void* d_ws, size_t ws_size,
                              hipStream_t stream) {
  const float* q  = (const float*)d_in[0];
  const float* k  = (const float*)d_in[1];
  const float* v  = (const float*)d_in[2];
  const float* wq = (const float*)d_in[3];
  const float* wk = (const float*)d_in[4];
  const float* wv = (const float*)d_in[5];
  float* out = (float*)d_out;

  u16* qkv = (u16*)d_ws;                 // 3 * NELEM
  u16* wT  = qkv + 3 * NELEM;            // 3 * WELEM
  u16* emb = wT + 3 * WELEM;             // 3 * NELEM
  u16* vT  = qkv;                        // reuse qkv region after GEMM

  k_convert<<<dim3(2048, 3), 256, 0, stream>>>(q, k, v, qkv);
  k_transposeW<<<dim3(16, 16, 3), 256, 0, stream>>>(wq, wk, wv, wT);
  k_gemm<<<dim3(HID / 128, MTOT / 128, 3), 256, 0, stream>>>(qkv, wT, emb);
  k_transposeV<<<dim3(S_ / 64, NH, B_), 256, 0, stream>>>(emb + 2 * NELEM, vT);
  k_attn<<<dim3(S_ / 64, B_ * NH), 256, 0, stream>>>(emb, emb + NELEM, vT, out);
}

// Round 8
// 117.473 us; speedup vs baseline: 1.0906x; 1.0906x over previous
//
#include <hip/hip_runtime.h>
#include <stdint.h>

// Problem constants
#define B_   2
#define S_   2048
#define HID  1024
#define NH   16
#define CH   64
#define MTOT (B_ * S_)          // 4096 rows
#define NELEM ((size_t)MTOT * HID)   // 4,194,304 per matrix
#define WELEM ((size_t)HID * HID)    // 1,048,576 per weight

typedef unsigned short u16;
typedef __attribute__((ext_vector_type(4))) float f32x4;
typedef __attribute__((ext_vector_type(8))) short s16x8;

// ---------- helpers ----------
__device__ __forceinline__ u16 f2bf(float f) {
  union { float f; unsigned u; } v; v.f = f;
  unsigned u = v.u;
  return (u16)((u + 0x7FFFu + ((u >> 16) & 1u)) >> 16);  // RNE (R3/R4-verified)
}

__device__ __forceinline__ f32x4 mfma16(s16x8 a, s16x8 b, f32x4 c) {
  // v_mfma_f32_16x16x32_bf16: A row = lane&15, k = (lane>>4)*8+j (contig 16B);
  // B col = lane&15, same k; D col = lane&15, row = (lane>>4)*4+reg (m89-verified).
  asm("v_mfma_f32_16x16x32_bf16 %0, %1, %2, %0" : "+v"(c) : "v"(a), "v"(b));
  return c;
}

// Hazard-hardened variant (R7-PROVEN fix for the R5/R6 failures):
//  - s_nop 1 guards the CDNA "VALU write -> MFMA read SrcA/B/C" 2-cycle rule
//    (per-step acc={0} v_movs can be scheduled adjacent to the MFMA).
//  - "+&v" early-clobber forbids aliasing A/B inputs with the D output.
__device__ __forceinline__ f32x4 mfma16h(s16x8 a, s16x8 b, f32x4 c) {
  asm("s_nop 1\n\tv_mfma_f32_16x16x32_bf16 %0, %1, %2, %0"
      : "+&v"(c) : "v"(a), "v"(b));
  return c;
}

__device__ __forceinline__ void mfma_fence() {
  asm volatile("s_nop 7\n\ts_nop 7" ::: );
}

__device__ __forceinline__ void gload_lds16(const u16* g, u16* l) {
  __builtin_amdgcn_global_load_lds((const __attribute__((address_space(1))) void*)g,
                                   (__attribute__((address_space(3))) void*)l,
                                   16, 0, 0);
}

// ---------- kernel 1: fp32 -> bf16 convert of q,k,v ----------
__global__ __launch_bounds__(256) void k_convert(const float* __restrict__ a,
                                                 const float* __restrict__ b,
                                                 const float* __restrict__ c,
                                                 u16* __restrict__ out) {
  const float* src = (blockIdx.y == 0) ? a : (blockIdx.y == 1) ? b : c;
  u16* dst = out + (size_t)blockIdx.y * NELEM;
  size_t i = ((size_t)blockIdx.x * 256 + threadIdx.x) * 8;
  f32x4 v0 = *(const f32x4*)(src + i);
  f32x4 v1 = *(const f32x4*)(src + i + 4);
  s16x8 r;
#pragma unroll
  for (int k = 0; k < 4; ++k) { r[k] = (short)f2bf(v0[k]); r[4 + k] = (short)f2bf(v1[k]); }
  *(s16x8*)(dst + i) = r;
}

// ---------- kernel 2: W (fp32 [K][N]) -> W^T (bf16 [N][K]) ----------
__global__ __launch_bounds__(256) void k_transposeW(const float* __restrict__ w0,
                                                    const float* __restrict__ w1,
                                                    const float* __restrict__ w2,
                                                    u16* __restrict__ wT) {
  const float* w = (blockIdx.z == 0) ? w0 : (blockIdx.z == 1) ? w1 : w2;
  u16* o = wT + (size_t)blockIdx.z * WELEM;
  __shared__ u16 tile[64][65];
  int x = threadIdx.x & 63, y = threadIdx.x >> 6;
  int r0 = blockIdx.x * 64, c0 = blockIdx.y * 64;
#pragma unroll
  for (int i = 0; i < 16; ++i) {
    int r = i * 4 + y;
    tile[r][x] = f2bf(w[(size_t)(r0 + r) * HID + c0 + x]);
  }
  __syncthreads();
#pragma unroll
  for (int i = 0; i < 16; ++i) {
    int cc = i * 4 + y;
    o[(size_t)(c0 + cc) * HID + r0 + x] = tile[x][cc];
  }
}

// ---------- kernel 3: bf16 GEMM  C[M,N] = A[M,K] @ (BT[N,K])^T ----------
// m97 structure: 128x128 tile, BK=32, 4 waves in 2x2, global_load_lds width 16.
// z==0 (emb_q) is scaled by 1/sqrt(CH) so attention needs no per-score scale.
__global__ __launch_bounds__(256) void k_gemm(const u16* __restrict__ Aall,
                                              const u16* __restrict__ BTall,
                                              u16* __restrict__ Call) {
  const u16* A  = Aall  + (size_t)blockIdx.z * NELEM;
  const u16* BT = BTall + (size_t)blockIdx.z * WELEM;
  u16*       C  = Call  + (size_t)blockIdx.z * NELEM;
  int row0 = blockIdx.y * 128, col0 = blockIdx.x * 128;

  __shared__ __align__(16) u16 sA[128 * 32];
  __shared__ __align__(16) u16 sB[128 * 32];

  int t = threadIdx.x;
  int wave = t >> 6, lane = t & 63;
  int lrow = lane & 15, lhi = lane >> 4;
  int wr = wave >> 1, wc = wave & 1;

  f32x4 acc[4][4] = {};

  for (int kt = 0; kt < HID; kt += 32) {
#pragma unroll
    for (int r = 0; r < 2; ++r) {
      int idx = r * 256 + t;
      int srow = idx >> 2, scol = (idx & 3) << 3;
      int ldsoff = (r * 256 + wave * 64) * 8;   // wave-uniform LDS base
      gload_lds16(A  + (size_t)(row0 + srow) * HID + kt + scol, sA + ldsoff);
      gload_lds16(BT + (size_t)(col0 + srow) * HID + kt + scol, sB + ldsoff);
    }
    __syncthreads();
    s16x8 af[4], bfr[4];
#pragma unroll
    for (int m = 0; m < 4; ++m)
      af[m] = *(const s16x8*)&sA[(wr * 64 + m * 16 + lrow) * 32 + lhi * 8];
#pragma unroll
    for (int n = 0; n < 4; ++n)
      bfr[n] = *(const s16x8*)&sB[(wc * 64 + n * 16 + lrow) * 32 + lhi * 8];
#pragma unroll
    for (int m = 0; m < 4; ++m)
#pragma unroll
      for (int n = 0; n < 4; ++n)
        acc[m][n] = mfma16(af[m], bfr[n], acc[m][n]);
    __syncthreads();
  }
  mfma_fence();
  float scl = (blockIdx.z == 0) ? 0.125f : 1.0f;   // fold 1/sqrt(64) into emb_q
#pragma unroll
  for (int m = 0; m < 4; ++m)
#pragma unroll
    for (int n = 0; n < 4; ++n)
#pragma unroll
      for (int j = 0; j < 4; ++j) {
        int rr = row0 + wr * 64 + m * 16 + lhi * 4 + j;
        int cc = col0 + wc * 64 + n * 16 + lrow;
        C[(size_t)rr * HID + cc] = f2bf(acc[m][n][j] * scl);
      }
}

// ---------- kernel 4: emb_v [B*S, HID] -> V^T [B,H,CH,S] ----------
__global__ __launch_bounds__(256) void k_transposeV(const u16* __restrict__ ev,
                                                    u16* __restrict__ vt) {
  int x = threadIdx.x & 63, y = threadIdx.x >> 6;
  int s0 = blockIdx.x * 64;
  int h = blockIdx.y, b = blockIdx.z;
  __shared__ u16 tile[64][65];
#pragma unroll
  for (int i = 0; i < 16; ++i) {
    int r = i * 4 + y;
    tile[r][x] = ev[(size_t)(b * S_ + s0 + r) * HID + h * CH + x];
  }
  __syncthreads();
#pragma unroll
  for (int i = 0; i < 16; ++i) {
    int cc = i * 4 + y;
    vt[((size_t)(b * NH + h) * CH + cc) * S_ + s0 + x] = tile[x][cc];
  }
}

// ---------- kernel 5: causal flash attention ----------
// R5 structure re-landed with the R7-proven hazard-hardened MFMA:
// block = 8 waves x 16 q-rows (QTILE=128), KVBLK=64, K/V LDS double-buffered
// (global_load_lds, XOR-swizzled; wave w stages K-chunk w and V-chunk w),
// fixed-max softmax, deferred row-sum. 2 blocks/CU x 8 waves = 4 waves/SIMD.
__global__ __launch_bounds__(512) void k_attn(const u16* __restrict__ eq,
                                              const u16* __restrict__ ek,
                                              const u16* __restrict__ vt,
                                              float* __restrict__ out) {
  int bh = blockIdx.y;                 // b*NH + h
  int b = bh >> 4, h = bh & 15;
  // causal load balance: pair q-tile k with 15-k across the two bh halves
  int qt = (blockIdx.y & 16) ? (int)blockIdx.x : (15 - (int)blockIdx.x);
  int q0b = qt * 128;
  int wave = threadIdx.x >> 6, lane = threadIdx.x & 63;
  int lrow = lane & 15, lhi = lane >> 4;
  int q0w = q0b + wave * 16;

  __shared__ __align__(16) u16 sK[2][64 * 64];
  __shared__ __align__(16) u16 sV[2][64 * 64];
  __shared__ __align__(16) u16 pbuf[8][16 * 72];   // P bounce, stride 72 (pad)
  u16* pb = pbuf[wave];

  const u16* gK = ek + (size_t)(b * S_) * HID + h * CH;
  const u16* gV = vt + (size_t)bh * CH * S_;

  // Q fragments held in registers (emb_q pre-scaled by 1/8 in GEMM)
  s16x8 qf[2];
  {
    size_t qbase = (size_t)(b * S_ + q0w + lrow) * HID + h * CH;
    qf[0] = *(const s16x8*)(eq + qbase + lhi * 8);
    qf[1] = *(const s16x8*)(eq + qbase + 32 + lhi * 8);
  }

  f32x4 o[4] = {};
  float lsum[4] = {0.f, 0.f, 0.f, 0.f};

  // staging lane mapping: chunk c covers rows c*8..c*8+7; wave stages chunk wave
  int lr8 = lane >> 3, slot = lane & 7;
  int co = ((slot ^ lr8) << 3);     // inverse-swizzled source column (elems)

  // prologue: stage tile 0 (wave w -> chunk w of K and of V)
  gload_lds16(gK + (size_t)(wave * 8 + lr8) * HID + co, &sK[0][wave * 512]);
  gload_lds16(gV + (size_t)(wave * 8 + lr8) * S_  + co, &sV[0][wave * 512]);

  int nsteps = q0b / 64 + 2;
  for (int st = 0; st < nsteps; ++st) {
    int tb = st * 64;
    __syncthreads();                       // stage(st) complete in all waves
    if (st + 1 < nsteps) {                 // prefetch next tile into other buf
      int tb2 = tb + 64;
      int bufn = (st + 1) & 1;
      gload_lds16(gK + (size_t)(tb2 + wave * 8 + lr8) * HID + co, &sK[bufn][wave * 512]);
      // V^T: row = channel (stride S_), seq offset tb2 goes in the COLUMN
      gload_lds16(gV + (size_t)(wave * 8 + lr8) * S_ + tb2 + co, &sV[bufn][wave * 512]);
    }
    if (tb > q0w + 15) continue;           // fully masked for this wave

    const u16* kb = sK[st & 1];
    const u16* vb = sV[st & 1];

    // ---- QK^T: 8 MFMA ----
    s16x8 kf[4][2];
#pragma unroll
    for (int kvf = 0; kvf < 4; ++kvf) {
      int row = kvf * 16 + lrow;
      int sw = row & 7;
#pragma unroll
      for (int ks = 0; ks < 2; ++ks)
        kf[kvf][ks] = *(const s16x8*)(kb + row * 64 + (((ks * 4 + lhi) ^ sw) << 3));
    }
    f32x4 sc[4];
#pragma unroll
    for (int kvf = 0; kvf < 4; ++kvf) {
      f32x4 acc = {0.f, 0.f, 0.f, 0.f};
      acc = mfma16h(qf[0], kf[kvf][0], acc);
      acc = mfma16h(qf[1], kf[kvf][1], acc);
      sc[kvf] = acc;
    }
    mfma_fence();

    // ---- softmax numerators (fixed max = 0), deferred denominator ----
    bool need_mask = (tb + 63 > q0w);
#pragma unroll
    for (int j = 0; j < 4; ++j) {
      float v0 = sc[0][j], v1 = sc[1][j], v2 = sc[2][j], v3 = sc[3][j];
      if (need_mask) {
        int qpos = q0w + lhi * 4 + j;
        if (tb + lrow > qpos)      v0 = -3.0e38f;
        if (tb + 16 + lrow > qpos) v1 = -3.0e38f;
        if (tb + 32 + lrow > qpos) v2 = -3.0e38f;
        if (tb + 48 + lrow > qpos) v3 = -3.0e38f;
      }
      float e0 = __expf(v0), e1 = __expf(v1);
      float e2 = __expf(v2), e3 = __expf(v3);
      lsum[j] += (e0 + e1) + (e2 + e3);
      int prow = (lhi * 4 + j) * 72;
      pb[prow + lrow]      = f2bf(e0);
      pb[prow + 16 + lrow] = f2bf(e1);
      pb[prow + 32 + lrow] = f2bf(e2);
      pb[prow + 48 + lrow] = f2bf(e3);
    }

    // ---- PV: 8 MFMA ----
#pragma unroll
    for (int kvs = 0; kvs < 2; ++kvs) {
      s16x8 pa = *(const s16x8*)&pb[lrow * 72 + kvs * 32 + lhi * 8];
#pragma unroll
      for (int ct = 0; ct < 4; ++ct) {
        int row = ct * 16 + lrow;
        s16x8 vf = *(const s16x8*)(vb + row * 64 + (((kvs * 4 + lhi) ^ (row & 7)) << 3));
        o[ct] = mfma16h(pa, vf, o[ct]);
      }
    }
  }
  mfma_fence();

  // deferred row-sum reduce (once, not per step)
#pragma unroll
  for (int j = 0; j < 4; ++j) {
    float rs = lsum[j];
    rs += __shfl_xor(rs, 1);
    rs += __shfl_xor(rs, 2);
    rs += __shfl_xor(rs, 4);
    rs += __shfl_xor(rs, 8);
    lsum[j] = rs;
  }

#pragma unroll
  for (int j = 0; j < 4; ++j) {
    float inv = 1.0f / lsum[j];
    int q = q0w + lhi * 4 + j;
    float* op = out + (size_t)(b * S_ + q) * HID + h * CH + lrow;
#pragma unroll
    for (int ct = 0; ct < 4; ++ct)
      op[ct * 16] = o[ct][j] * inv;
  }
}

// ---------- launch ----------
extern "C" void kernel_launch(void* const* d_in, const int* in_sizes, int n_in,
                              void* d_out, int out_size, void* d_ws, size_t ws_size,
                              hipStream_t stream) {
  const float* q  = (const float*)d_in[0];
  const float* k  = (const float*)d_in[1];
  const float* v  = (const float*)d_in[2];
  const float* wq = (const float*)d_in[3];
  const float* wk = (const float*)d_in[4];
  const float* wv = (const float*)d_in[5];
  float* out = (float*)d_out;

  u16* qkv = (u16*)d_ws;                 // 3 * NELEM
  u16* wT  = qkv + 3 * NELEM;            // 3 * WELEM
  u16* emb = wT + 3 * WELEM;             // 3 * NELEM
  u16* vT  = qkv;                        // reuse qkv region after GEMM

  k_convert<<<dim3(2048, 3), 256, 0, stream>>>(q, k, v, qkv);
  k_transposeW<<<dim3(16, 16, 3), 256, 0, stream>>>(wq, wk, wv, wT);
  k_gemm<<<dim3(HID / 128, MTOT / 128, 3), 256, 0, stream>>>(qkv, wT, emb);
  k_transposeV<<<dim3(S_ / 64, NH, B_), 256, 0, stream>>>(emb + 2 * NELEM, vT);
  k_attn<<<dim3(S_ / 128, B_ * NH), 512, 0, stream>>>(emb, emb + NELEM, vT, out);
}

// Round 9
// 105.241 us; speedup vs baseline: 1.2173x; 1.1162x over previous
//
#include <hip/hip_runtime.h>
#include <stdint.h>

// Problem constants
#define B_   2
#define S_   2048
#define HID  1024
#define NH   16
#define CH   64
#define MTOT (B_ * S_)          // 4096 rows
#define NELEM ((size_t)MTOT * HID)   // 4,194,304 per matrix
#define WELEM ((size_t)HID * HID)    // 1,048,576 per weight

typedef unsigned short u16;
typedef unsigned int u32;
typedef __attribute__((ext_vector_type(4))) float f32x4;
typedef __attribute__((ext_vector_type(8))) short s16x8;
typedef __attribute__((ext_vector_type(4))) short s16x4;

// ---------- helpers ----------
__device__ __forceinline__ u16 f2bf(float f) {
  union { float f; unsigned u; } v; v.f = f;
  unsigned u = v.u;
  return (u16)((u + 0x7FFFu + ((u >> 16) & 1u)) >> 16);  // RNE (R3/R4-verified)
}

__device__ __forceinline__ f32x4 mfma16(s16x8 a, s16x8 b, f32x4 c) {
  // v_mfma_f32_16x16x32_bf16: A row = lane&15, k = (lane>>4)*8+j (contig 16B);
  // B col = lane&15, same k; D col = lane&15, row = (lane>>4)*4+reg (m89-verified).
  asm("v_mfma_f32_16x16x32_bf16 %0, %1, %2, %0" : "+v"(c) : "v"(a), "v"(b));
  return c;
}

// Hazard-hardened variants (R7-PROVEN fix): s_nop 1 guards VALU-write ->
// MFMA-read (2-cycle rule); "+&v" early-clobber forbids A/B aliasing D.
__device__ __forceinline__ f32x4 mfma16h(s16x8 a, s16x8 b, f32x4 c) {
  asm("s_nop 1\n\tv_mfma_f32_16x16x32_bf16 %0, %1, %2, %0"
      : "+&v"(c) : "v"(a), "v"(b));
  return c;
}

// 16x16x16 bf16 MFMA (A/B: 2 VGPRs = 4 bf16, k = (lane>>4)*4 + elem).
__device__ __forceinline__ f32x4 mfma16k16h(s16x4 a, s16x4 b, f32x4 c) {
  asm("s_nop 1\n\tv_mfma_f32_16x16x16_bf16 %0, %1, %2, %0"
      : "+&v"(c) : "v"(a), "v"(b));
  return c;
}

__device__ __forceinline__ u32 cvtpk(float lo, float hi) {
  u32 r;
  asm("v_cvt_pk_bf16_f32 %0, %1, %2" : "=v"(r) : "v"(lo), "v"(hi));
  return r;
}

__device__ __forceinline__ void mfma_fence() {
  asm volatile("s_nop 7\n\ts_nop 7" ::: );
}

__device__ __forceinline__ void gload_lds16(const u16* g, u16* l) {
  __builtin_amdgcn_global_load_lds((const __attribute__((address_space(1))) void*)g,
                                   (__attribute__((address_space(3))) void*)l,
                                   16, 0, 0);
}

// ---------- kernel 1: fp32 -> bf16 convert of q,k,v ----------
__global__ __launch_bounds__(256) void k_convert(const float* __restrict__ a,
                                                 const float* __restrict__ b,
                                                 const float* __restrict__ c,
                                                 u16* __restrict__ out) {
  const float* src = (blockIdx.y == 0) ? a : (blockIdx.y == 1) ? b : c;
  u16* dst = out + (size_t)blockIdx.y * NELEM;
  size_t i = ((size_t)blockIdx.x * 256 + threadIdx.x) * 8;
  f32x4 v0 = *(const f32x4*)(src + i);
  f32x4 v1 = *(const f32x4*)(src + i + 4);
  s16x8 r;
#pragma unroll
  for (int k = 0; k < 4; ++k) { r[k] = (short)f2bf(v0[k]); r[4 + k] = (short)f2bf(v1[k]); }
  *(s16x8*)(dst + i) = r;
}

// ---------- kernel 2: W (fp32 [K][N]) -> W^T (bf16 [N][K]) ----------
__global__ __launch_bounds__(256) void k_transposeW(const float* __restrict__ w0,
                                                    const float* __restrict__ w1,
                                                    const float* __restrict__ w2,
                                                    u16* __restrict__ wT) {
  const float* w = (blockIdx.z == 0) ? w0 : (blockIdx.z == 1) ? w1 : w2;
  u16* o = wT + (size_t)blockIdx.z * WELEM;
  __shared__ u16 tile[64][65];
  int x = threadIdx.x & 63, y = threadIdx.x >> 6;
  int r0 = blockIdx.x * 64, c0 = blockIdx.y * 64;
#pragma unroll
  for (int i = 0; i < 16; ++i) {
    int r = i * 4 + y;
    tile[r][x] = f2bf(w[(size_t)(r0 + r) * HID + c0 + x]);
  }
  __syncthreads();
#pragma unroll
  for (int i = 0; i < 16; ++i) {
    int cc = i * 4 + y;
    o[(size_t)(c0 + cc) * HID + r0 + x] = tile[x][cc];
  }
}

// ---------- kernel 3: bf16 GEMM  C[M,N] = A[M,K] @ (BT[N,K])^T ----------
// m97 structure. z==0 (emb_q) scaled by 1/8. z==2 (emb_v) is written in
// PACKED V-FRAG layout for the attention PV mfma_16x16x16 B-operand:
// vfrag[bh][t/16][chblk(4)][hi(4)][ch16(16)][4 bf16 of t%16 = hi*4+0..3].
// The GEMM D-frag already holds 4 consecutive t-rows per lane -> 1 uint2
// store per (m,n) replaces 4 scalar stores, and k_transposeV is deleted.
__global__ __launch_bounds__(256) void k_gemm(const u16* __restrict__ Aall,
                                              const u16* __restrict__ BTall,
                                              u16* __restrict__ Call,
                                              u16* __restrict__ Vfrag) {
  const u16* A  = Aall  + (size_t)blockIdx.z * NELEM;
  const u16* BT = BTall + (size_t)blockIdx.z * WELEM;
  u16*       C  = Call  + (size_t)blockIdx.z * NELEM;
  int row0 = blockIdx.y * 128, col0 = blockIdx.x * 128;

  __shared__ __align__(16) u16 sA[128 * 32];
  __shared__ __align__(16) u16 sB[128 * 32];

  int t = threadIdx.x;
  int wave = t >> 6, lane = t & 63;
  int lrow = lane & 15, lhi = lane >> 4;
  int wr = wave >> 1, wc = wave & 1;

  f32x4 acc[4][4] = {};

  for (int kt = 0; kt < HID; kt += 32) {
#pragma unroll
    for (int r = 0; r < 2; ++r) {
      int idx = r * 256 + t;
      int srow = idx >> 2, scol = (idx & 3) << 3;
      int ldsoff = (r * 256 + wave * 64) * 8;   // wave-uniform LDS base
      gload_lds16(A  + (size_t)(row0 + srow) * HID + kt + scol, sA + ldsoff);
      gload_lds16(BT + (size_t)(col0 + srow) * HID + kt + scol, sB + ldsoff);
    }
    __syncthreads();
    s16x8 af[4], bfr[4];
#pragma unroll
    for (int m = 0; m < 4; ++m)
      af[m] = *(const s16x8*)&sA[(wr * 64 + m * 16 + lrow) * 32 + lhi * 8];
#pragma unroll
    for (int n = 0; n < 4; ++n)
      bfr[n] = *(const s16x8*)&sB[(wc * 64 + n * 16 + lrow) * 32 + lhi * 8];
#pragma unroll
    for (int m = 0; m < 4; ++m)
#pragma unroll
      for (int n = 0; n < 4; ++n)
        acc[m][n] = mfma16(af[m], bfr[n], acc[m][n]);
    __syncthreads();
  }
  mfma_fence();
  if (blockIdx.z == 2) {
    // packed V-frag epilogue
#pragma unroll
    for (int m = 0; m < 4; ++m)
#pragma unroll
      for (int n = 0; n < 4; ++n) {
        int rr = row0 + wr * 64 + m * 16 + lhi * 4;       // t-row of j=0
        int cc = col0 + wc * 64 + n * 16 + lrow;          // hidden col
        int bb = rr >> 11, tt = rr & 2047;
        int hh = cc >> 6, chl = cc & 63;
        size_t off = ((size_t)(bb * NH + hh)) * ((size_t)CH * S_) +
                     (size_t)(((tt >> 4) * 4 + (chl >> 4)) * 256 +
                              ((tt >> 2) & 3) * 64 + (chl & 15) * 4);
        u32 w0 = (u32)f2bf(acc[m][n][0]) | ((u32)f2bf(acc[m][n][1]) << 16);
        u32 w1 = (u32)f2bf(acc[m][n][2]) | ((u32)f2bf(acc[m][n][3]) << 16);
        uint2 w; w.x = w0; w.y = w1;
        *(uint2*)&Vfrag[off] = w;
      }
  } else {
    float scl = (blockIdx.z == 0) ? 0.125f : 1.0f;   // fold 1/sqrt(64) into emb_q
#pragma unroll
    for (int m = 0; m < 4; ++m)
#pragma unroll
      for (int n = 0; n < 4; ++n)
#pragma unroll
        for (int j = 0; j < 4; ++j) {
          int rr = row0 + wr * 64 + m * 16 + lhi * 4 + j;
          int cc = col0 + wc * 64 + n * 16 + lrow;
          C[(size_t)rr * HID + cc] = f2bf(acc[m][n][j] * scl);
        }
  }
}

// ---------- kernel 4: causal flash attention ----------
// 8 waves x 16 q-rows (QTILE=128), KVBLK=64, fixed-max softmax, deferred
// row-sum. LDS-traffic-minimized: QK^T computed SWAPPED (A=K, B=Q) so the
// D fragment (q=lane&15, t=lhi*4+j) IS the mfma_16x16x16 A-frag layout;
// P converts in-register via v_cvt_pk_bf16_f32 — NO LDS P-bounce. V comes
// pre-packed (k_gemm z==2) as the x16 B-frag: 16 linear conflict-free
// ds_read_b64 per step. LDS: sK 16KB (swizzled) + sV 16KB (linear) = 32KB.
__global__ __launch_bounds__(512) void k_attn(const u16* __restrict__ eq,
                                              const u16* __restrict__ ek,
                                              const u16* __restrict__ vf,
                                              float* __restrict__ out) {
  int bh = blockIdx.y;                 // b*NH + h
  int b = bh >> 4, h = bh & 15;
  // causal load balance: pair q-tile k with 15-k across the two bh halves
  int qt = (blockIdx.y & 16) ? (int)blockIdx.x : (15 - (int)blockIdx.x);
  int q0b = qt * 128;
  int wave = threadIdx.x >> 6, lane = threadIdx.x & 63;
  int lrow = lane & 15, lhi = lane >> 4;
  int q0w = q0b + wave * 16;

  __shared__ __align__(16) u16 sK[2][64 * 64];
  __shared__ __align__(16) u16 sV[2][4096];

  const u16* gK = ek + (size_t)(b * S_) * HID + h * CH;
  const u16* gV = vf + (size_t)bh * ((size_t)CH * S_);

  // Q fragments (emb_q pre-scaled by 1/8). Same register content serves as
  // the swapped-QK B-frag (col=q=lane&15, k=ch=lhi*8+j).
  s16x8 qf[2];
  {
    size_t qbase = (size_t)(b * S_ + q0w + lrow) * HID + h * CH;
    qf[0] = *(const s16x8*)(eq + qbase + lhi * 8);
    qf[1] = *(const s16x8*)(eq + qbase + 32 + lhi * 8);
  }

  f32x4 o[4] = {};                 // o[chblk]: D col=ch16=lrow, row=q=lhi*4+reg
  float lsum = 0.0f;               // per-lane partial row-sum for q = lrow

  // K staging lane mapping (XOR-swizzled; chunk = 8 t-rows; wave stages chunk w)
  int lr8 = lane >> 3, slot = lane & 7;
  int co = ((slot ^ lr8) << 3);    // inverse-swizzled source column (elems)

  // prologue: stage tile 0
  gload_lds16(gK + (size_t)(wave * 8 + lr8) * HID + co, &sK[0][wave * 512]);
  gload_lds16(gV + (size_t)wave * 512 + lane * 8, &sV[0][wave * 512]);

  int nsteps = q0b / 64 + 2;
  for (int st = 0; st < nsteps; ++st) {
    int tb = st * 64;
    __syncthreads();                       // stage(st) complete in all waves
    if (st + 1 < nsteps) {                 // prefetch next tile into other buf
      int tb2 = tb + 64;
      int bufn = (st + 1) & 1;
      gload_lds16(gK + (size_t)(tb2 + wave * 8 + lr8) * HID + co, &sK[bufn][wave * 512]);
      gload_lds16(gV + (size_t)(tb2 >> 4) * 1024 + wave * 512 + lane * 8,
                  &sV[bufn][wave * 512]);
    }
    if (tb > q0w + 15) continue;           // fully masked for this wave

    const u16* kb = sK[st & 1];
    const u16* vb = sV[st & 1];

    // ---- QK^T swapped: 8 MFMA; p[kvf][j] = S[t=tb+kvf*16+lhi*4+j][q=q0w+lrow]
    f32x4 p[4];
#pragma unroll
    for (int kvf = 0; kvf < 4; ++kvf) {
      int row = kvf * 16 + lrow;
      int sw = row & 7;
      s16x8 k0 = *(const s16x8*)(kb + row * 64 + ((lhi ^ sw) << 3));
      s16x8 k1 = *(const s16x8*)(kb + row * 64 + (((4 + lhi) ^ sw) << 3));
      f32x4 acc = {0.f, 0.f, 0.f, 0.f};
      acc = mfma16h(k0, qf[0], acc);
      acc = mfma16h(k1, qf[1], acc);
      p[kvf] = acc;
    }
    mfma_fence();

    // ---- softmax numerators (fixed max = 0) -> in-register PV A-frags ----
    bool need_mask = (tb + 63 > q0w);
    s16x4 pa[4];
#pragma unroll
    for (int kvf = 0; kvf < 4; ++kvf) {
      float e[4];
#pragma unroll
      for (int j = 0; j < 4; ++j) {
        float v = p[kvf][j];
        if (need_mask && (tb + kvf * 16 + lhi * 4 + j > q0w + lrow)) v = -3.0e38f;
        e[j] = __expf(v);
      }
      lsum += (e[0] + e[1]) + (e[2] + e[3]);
      union { u32 u[2]; s16x4 v4; } pk;
      pk.u[0] = cvtpk(e[0], e[1]);
      pk.u[1] = cvtpk(e[2], e[3]);
      pa[kvf] = pk.v4;
    }

    // ---- PV: 16 x mfma_16x16x16, V read as linear b64 B-frags ----
#pragma unroll
    for (int n = 0; n < 4; ++n)
#pragma unroll
      for (int kvf = 0; kvf < 4; ++kvf) {
        s16x4 vfr = *(const s16x4*)&vb[(kvf * 4 + n) * 256 + lhi * 64 + lrow * 4];
        o[n] = mfma16k16h(pa[kvf], vfr, o[n]);
      }
  }
  mfma_fence();

  // reduce lsum across the 4 hi-groups: lane ends with total for q = lrow
  lsum += __shfl_xor(lsum, 16);
  lsum += __shfl_xor(lsum, 32);

#pragma unroll
  for (int j = 0; j < 4; ++j) {
    float ls = __shfl(lsum, lhi * 4 + j);   // total for q-row lhi*4+j
    float inv = 1.0f / ls;
    int q = q0w + lhi * 4 + j;
    float* op = out + (size_t)(b * S_ + q) * HID + h * CH + lrow;
#pragma unroll
    for (int n = 0; n < 4; ++n)
      op[n * 16] = o[n][j] * inv;
  }
}

// ---------- launch ----------
extern "C" void kernel_launch(void* const* d_in, const int* in_sizes, int n_in,
                              void* d_out, int out_size, void* d_ws, size_t ws_size,
                              hipStream_t stream) {
  const float* q  = (const float*)d_in[0];
  const float* k  = (const float*)d_in[1];
  const float* v  = (const float*)d_in[2];
  const float* wq = (const float*)d_in[3];
  const float* wk = (const float*)d_in[4];
  const float* wv = (const float*)d_in[5];
  float* out = (float*)d_out;

  u16* qkv = (u16*)d_ws;                 // 3 * NELEM
  u16* wT  = qkv + 3 * NELEM;            // 3 * WELEM
  u16* emb = wT + 3 * WELEM;             // 3 * NELEM (z=2 slot holds V-frag)
  u16* vfr = emb + 2 * NELEM;            // packed V-frag written by k_gemm z==2

  k_convert<<<dim3(2048, 3), 256, 0, stream>>>(q, k, v, qkv);
  k_transposeW<<<dim3(16, 16, 3), 256, 0, stream>>>(wq, wk, wv, wT);
  k_gemm<<<dim3(HID / 128, MTOT / 128, 3), 256, 0, stream>>>(qkv, wT, emb, vfr);
  k_attn<<<dim3(S_ / 128, B_ * NH), 512, 0, stream>>>(emb, emb + NELEM, vfr, out);
}